// Round 13
// baseline (4965.818 us; speedup 1.0000x reference)
//
#include <hip/hip_runtime.h>

typedef unsigned short u16;
typedef unsigned int u32;
typedef __attribute__((ext_vector_type(8))) short bf16x8;
typedef __attribute__((ext_vector_type(4))) float f32x4;
typedef __attribute__((ext_vector_type(2))) u32 u32x2;
typedef const __attribute__((address_space(1))) void* gas1_t;
typedef __attribute__((address_space(3))) void* las3_t;

// Problem dims
#define T_LEN 512
#define B_SZ  64
#define D_SZ  1024
#define H_SZ  1024

// workspace layout (bytes), all 256-aligned
#define OFF_WX    0UL           // 8 MiB  bf16 Wx  [4096][1024]
#define OFF_WH    8388608UL     // 8 MiB  bf16 Wh  [4096][1024]
#define OFF_BIAS  16777216UL    // 16 KiB f32 bias[4096] = bx+bh
#define OFF_FLAGS 16793600UL    // 1 KiB: u32 cnt0 @ +0, cnt1 @ +256 (per-half barrier counters)
#define OFF_HROLL 16794624UL    // 64 MiB bf16 hroll[512][64][1024] (slot t = h input of step t)
#define OFF_XBF   83903488UL    // 64 MiB bf16 x [32768][1024]
#define OFF_XPROJ 151012352UL   // 256 MiB bf16 xprojP [512][128][64][8][4] ([t][hs][brow][jj][gate])

__device__ __forceinline__ u16 f2bf(float f) {
  u32 u = __builtin_bit_cast(u32, f);
  u += 0x7FFFu + ((u >> 16) & 1u);   // RNE
  return (u16)(u >> 16);
}
__device__ __forceinline__ float bf2f(u16 h) {
  u32 u = ((u32)h) << 16;
  return __builtin_bit_cast(float, u);
}

// ---------- phase 0: conversions ----------
__global__ __launch_bounds__(256) void cvt_f32_bf16(const float* __restrict__ in,
                                                    u16* __restrict__ out, int n) {
  int i = (blockIdx.x * 256 + threadIdx.x) * 4;
  if (i >= n) return;
  float4 v = *(const float4*)(in + i);
  ushort4 o;
  o.x = f2bf(v.x); o.y = f2bf(v.y); o.z = f2bf(v.z); o.w = f2bf(v.w);
  *(ushort4*)(out + i) = o;
}

__global__ __launch_bounds__(256) void bias_add(const float* __restrict__ a,
                                                const float* __restrict__ b,
                                                float* __restrict__ o) {
  int i = blockIdx.x * 256 + threadIdx.x;  // 4096 total
  o[i] = a[i] + b[i];
}

// ---------- phase 1: xproj = x @ Wx^T, written PERMUTED for the lstm reader ----------
// C layout: [t(512)][hs(128)][brow(64)][jj(8)][gate(4)]
__global__ __launch_bounds__(256) void gemm_xproj(const u16* __restrict__ A,
                                                  const u16* __restrict__ Bw,
                                                  u16* __restrict__ C) {
  __shared__ __align__(16) u16 As[128 * 64];
  __shared__ __align__(16) u16 Bs[128 * 64];
  int wg = blockIdx.x;
  int swz = (wg & 7) * 1024 + (wg >> 3);  // XCD-aware bijective (8192 % 8 == 0)
  int mb = swz >> 5;
  int nb = swz & 31;
  int tid = threadIdx.x;
  int lane = tid & 63;
  int w = tid >> 6;
  int wm = w >> 1, wn = w & 1;

  int srow = lane >> 3;
  int scol = (lane & 7) * 8;
  const u16* Abase = A + (size_t)(mb * 128) * 1024;
  const u16* Bbase = Bw + (size_t)(nb * 128) * 1024;

  f32x4 acc[4][4];
#pragma unroll
  for (int i = 0; i < 4; ++i)
#pragma unroll
    for (int j = 0; j < 4; ++j) acc[i][j] = f32x4{0.f, 0.f, 0.f, 0.f};

  for (int k0 = 0; k0 < 1024; k0 += 64) {
#pragma unroll
    for (int r = 0; r < 4; ++r) {
      int chunk = w * 4 + r;
      int row = chunk * 8 + srow;
      __builtin_amdgcn_global_load_lds((gas1_t)(const void*)(Abase + (size_t)row * 1024 + k0 + scol),
                                       (las3_t)(void*)(&As[chunk * 512]), 16, 0, 0);
      __builtin_amdgcn_global_load_lds((gas1_t)(const void*)(Bbase + (size_t)row * 1024 + k0 + scol),
                                       (las3_t)(void*)(&Bs[chunk * 512]), 16, 0, 0);
    }
    __syncthreads();
#pragma unroll
    for (int kk = 0; kk < 64; kk += 32) {
      bf16x8 af[4], bfr[4];
#pragma unroll
      for (int mt = 0; mt < 4; ++mt)
        af[mt] = *(const bf16x8*)&As[(wm * 64 + mt * 16 + (lane & 15)) * 64 + kk + ((lane >> 4) << 3)];
#pragma unroll
      for (int nt = 0; nt < 4; ++nt)
        bfr[nt] = *(const bf16x8*)&Bs[(wn * 64 + nt * 16 + (lane & 15)) * 64 + kk + ((lane >> 4) << 3)];
#pragma unroll
      for (int mt = 0; mt < 4; ++mt)
#pragma unroll
        for (int nt = 0; nt < 4; ++nt)
          acc[mt][nt] = __builtin_amdgcn_mfma_f32_16x16x32_bf16(af[mt], bfr[nt], acc[mt][nt], 0, 0, 0);
    }
    __syncthreads();
  }
  int crowbase = mb * 128 + wm * 64;
  int ccolbase = nb * 128 + wn * 64;
#pragma unroll
  for (int mt = 0; mt < 4; ++mt)
#pragma unroll
    for (int nt = 0; nt < 4; ++nt) {
      int col = ccolbase + nt * 16 + (lane & 15);
      int gate = col >> 10;
      int hc = col & 1023;
      size_t cb = (size_t)(hc >> 3) * 2048 + (size_t)(hc & 7) * 4 + gate;  // hs*64*32 + jj*4 + gate
#pragma unroll
      for (int r = 0; r < 4; ++r) {
        int row = crowbase + mt * 16 + ((lane >> 4) << 2) + r;
        C[(size_t)(row >> 6) * 262144 + cb + (size_t)(row & 63) * 32] = f2bf(acc[mt][nt][r]);
      }
    }
}

// ---------- phase 2: persistent sequential LSTM ----------
// 256 WGs x 256 threads (ALL 256 CUs; 1 WG/CU). WG = (bh, hw): batch-half bh
// (32 rows) x 8 h-cols (32 gate-cols). 4 waves x 4-way K-partition -- R2's
// proven per-WG layout on R12's proven transport:
//  - rolling h buffer, NORMAL CACHED loads (virgin addresses per launch),
//  - write-through sc0sc1 h stores + permuted-xproj prefetch + vmcnt(1),
//  - per-half LLC atomic-counter barrier (128 publishers/domain).
// LDS reduce: 16 frags, 32 b32 instrs/thread, row stride 20 (write banks
// exactly 2 lanes/bank = free; reads ~2-way) -- per-CU LDS time ~5x lower
// than R12's 64-frag/8-wave reduce.
__global__ __launch_bounds__(256, 2) void lstm_seq(const u16* __restrict__ xprojP,
                                                   const u16* __restrict__ Whb,
                                                   const float* __restrict__ bias,
                                                   u16* __restrict__ hroll,
                                                   u32* __restrict__ flags,
                                                   float* __restrict__ out) {
  __shared__ float pacc[16 * 320];  // 16 frags [kq][rt][nt], rows padded to 20
#define PIDX(frag, row, col) (((frag) * 320) + (row) * 20 + (col))
  int wg = blockIdx.x;     // 0..255
  int bh = wg >> 7;        // batch half (independent barrier domain)
  int hw = wg & 127;       // 8-col slice (cols hw*8 .. hw*8+7)
  int tid = threadIdx.x;   // 0..255
  int lane = tid & 63;
  int kq = tid >> 6;       // wave = K-slice, 0..3 (256 k-cols each)
  int kw = kq << 8;        // k base
  int hi8 = (lane >> 4) << 3;

  // Wh fragments, register-resident (R2-proven mapping):
  // wf[nt][ks]: gate-col c = nt*16 + (lane&15); wrow = gate*1024 + hw*8 + jj
  bf16x8 wf[2][8];
#pragma unroll
  for (int nt = 0; nt < 2; ++nt) {
    int c = nt * 16 + (lane & 15);
    int wrow = ((c >> 3) << 10) + (hw << 3) + (c & 7);
#pragma unroll
    for (int ks = 0; ks < 8; ++ks)
      wf[nt][ks] = *(const bf16x8*)&Whb[(size_t)wrow * 1024 + kw + ks * 32 + hi8];
  }

  int b = tid >> 3;                  // 0..31 batch row within half
  int jj = tid & 7;                  // h-col within slice
  int hrow = (bh << 5) + b;
  int hcol = (hw << 3) + jj;
  float bs0 = bias[hcol], bs1 = bias[1024 + hcol], bs2 = bias[2048 + hcol], bs3 = bias[3072 + hcol];
  float c_state = 0.f;
  int am_row0 = (bh << 5) + (lane & 15);
  int am_row1 = am_row0 + 16;
  int mI = b >> 4, r16 = b & 15;
  u32* cnt = flags + (bh << 6);      // per-half counter, 256 B apart

  // permuted xproj pointer; per-step stride 262144 elems (512 KB)
  const u16* xpt = xprojP + ((size_t)hw * 64 + hrow) * 32 + jj * 4;
  u32x2 pd = *(const u32x2*)xpt;     // t=0 prefetch (plain cached)

  for (int t = 0; t < T_LEN; ++t) {
    // ---- h load: NORMAL CACHED from rolling slot t (virgin addresses) ----
    const u16* hcur = hroll + (size_t)t * 65536;
    const u16* p0 = hcur + (size_t)am_row0 * 1024 + kw + hi8;
    const u16* p1 = hcur + (size_t)am_row1 * 1024 + kw + hi8;
    bf16x8 a0[8], a1[8];
#pragma unroll
    for (int ks = 0; ks < 8; ++ks) {
      a0[ks] = *(const bf16x8*)(p0 + ks * 32);
      a1[ks] = *(const bf16x8*)(p1 + ks * 32);
    }

    // ---- MFMA: 4 accs (2 row-frags x 2 col-tiles) over 8 k-steps ----
    f32x4 acc00 = f32x4{0.f, 0.f, 0.f, 0.f}, acc01 = acc00, acc10 = acc00, acc11 = acc00;
#pragma unroll
    for (int ks = 0; ks < 8; ++ks) {
      acc00 = __builtin_amdgcn_mfma_f32_16x16x32_bf16(a0[ks], wf[0][ks], acc00, 0, 0, 0);
      acc01 = __builtin_amdgcn_mfma_f32_16x16x32_bf16(a0[ks], wf[1][ks], acc01, 0, 0, 0);
      acc10 = __builtin_amdgcn_mfma_f32_16x16x32_bf16(a1[ks], wf[0][ks], acc10, 0, 0, 0);
      acc11 = __builtin_amdgcn_mfma_f32_16x16x32_bf16(a1[ks], wf[1][ks], acc11, 0, 0, 0);
    }
    // ---- per-wave partials -> LDS: frag = kq*4 + rt*2 + nt ----
    {
      int rbase = (lane >> 4) << 2;
      int cidx = lane & 15;
      int f0i = kq << 2;
#pragma unroll
      for (int r = 0; r < 4; ++r) {
        pacc[PIDX(f0i + 0, rbase + r, cidx)] = acc00[r];
        pacc[PIDX(f0i + 1, rbase + r, cidx)] = acc01[r];
        pacc[PIDX(f0i + 2, rbase + r, cidx)] = acc10[r];
        pacc[PIDX(f0i + 3, rbase + r, cidx)] = acc11[r];
      }
    }
    __syncthreads();
    // ---- reduce over 4 kq partials per gate ----
    float g[4];
#pragma unroll
    for (int f = 0; f < 4; ++f) {
      int c = f * 8 + jj;
      int ntf = c >> 4, c16 = c & 15;
      float s = 0.f;
#pragma unroll
      for (int k2 = 0; k2 < 4; ++k2)
        s += pacc[PIDX((k2 << 2) + (mI << 1) + ntf, r16, c16)];
      g[f] = s;
    }
    // tie the prefetched xproj dwords to a vmcnt before use (rule #18)
    asm volatile("s_waitcnt vmcnt(0)" : "+v"(pd));
    float gi = g[0] + bf2f((u16)(pd[0] & 0xFFFFu)) + bs0;
    float gf = g[1] + bf2f((u16)(pd[0] >> 16)) + bs1;
    float go = g[2] + bf2f((u16)(pd[1] & 0xFFFFu)) + bs2;
    float gc = g[3] + bf2f((u16)(pd[1] >> 16)) + bs3;
    float iv = 1.f / (1.f + __expf(-gi));
    float fv = 1.f / (1.f + __expf(-gf));
    float ov = 1.f / (1.f + __expf(-go));
    float cv = tanhf(gc);
    c_state = 1.f / (1.f + __expf(-(fv * c_state + iv * cv)));  // nonstandard, per reference
    float hn = tanhf(c_state) * ov;

    if (t == T_LEN - 1) {
      out[(size_t)hrow * 1024 + hcol] = hn;
    } else {
      // h store (write-through to slot t+1) + xproj(t+1) prefetch + counted
      // drain: vmcnt(1) retires the OLDER store; load flies through the poll.
      u16* hdst = hroll + (size_t)(t + 1) * 65536 + (size_t)hrow * 1024 + hcol;
      const u16* xnext = xpt + (size_t)(t + 1) * 262144;
      u32 hb = (u32)f2bf(hn);
      asm volatile(
          "global_store_short %1, %3, off sc0 sc1\n\t"
          "global_load_dwordx2 %0, %2, off\n\t"
          "s_waitcnt vmcnt(1)"
          : "=&v"(pd)
          : "v"(hdst), "v"(xnext), "v"(hb)
          : "memory");
      __syncthreads();  // all 4 waves' stores drained; pacc reads done
      // publish: fire-and-forget atomic increment (performed at the LLC)
      if (tid == 0) {
        u32 one = 1u;
        asm volatile("global_atomic_add %0, %1, off" :: "v"(cnt), "v"(one) : "memory");
        // poll: atomic read-at-LLC (add 0, sc0 returns old). One line, LLC-resident.
        u32 tgt = (u32)((t + 1) << 7);   // 128 publishers per domain
        u32 zero = 0u;
        u32 old;
        for (;;) {
          asm volatile("global_atomic_add %0, %1, %2, off sc0\n\ts_waitcnt vmcnt(0)"
                       : "=&v"(old) : "v"(cnt), "v"(zero) : "memory");
          if (old >= tgt) break;
        }
      }
      __syncthreads();
    }
  }
}

extern "C" void kernel_launch(void* const* d_in, const int* in_sizes, int n_in,
                              void* d_out, int out_size, void* d_ws, size_t ws_size,
                              hipStream_t stream) {
  const float* x  = (const float*)d_in[0];   // [512][64][1024]
  const float* Wx = (const float*)d_in[1];   // [4][1024][1024]
  const float* bx = (const float*)d_in[2];   // [4][1024]
  const float* Wh = (const float*)d_in[3];   // [4][1024][1024]
  const float* bh = (const float*)d_in[4];   // [4][1024]
  float* out = (float*)d_out;                // [64][1024]
  char* ws = (char*)d_ws;

  u16* wx_bf  = (u16*)(ws + OFF_WX);
  u16* wh_bf  = (u16*)(ws + OFF_WH);
  float* bias = (float*)(ws + OFF_BIAS);
  u32* flags  = (u32*)(ws + OFF_FLAGS);
  u16* hroll  = (u16*)(ws + OFF_HROLL);
  u16* x_bf   = (u16*)(ws + OFF_XBF);
  u16* xproj  = (u16*)(ws + OFF_XPROJ);

  // per-launch: zero counters (1 KiB) + rolling slot 0 (h_0 = 0, 128 KiB) -- contiguous
  hipMemsetAsync(ws + OFF_FLAGS, 0, 1024 + 131072, stream);

  cvt_f32_bf16<<<4096, 256, 0, stream>>>(Wx, wx_bf, 4194304);
  cvt_f32_bf16<<<4096, 256, 0, stream>>>(Wh, wh_bf, 4194304);
  bias_add<<<16, 256, 0, stream>>>(bx, bh, bias);
  cvt_f32_bf16<<<32768, 256, 0, stream>>>(x, x_bf, 33554432);
  gemm_xproj<<<8192, 256, 0, stream>>>(x_bf, wx_bf, xproj);
  lstm_seq<<<256, 256, 0, stream>>>(xproj, wh_bf, bias, hroll, flags, out);
}

// Round 14
// 3290.837 us; speedup vs baseline: 1.5090x; 1.5090x over previous
//
#include <hip/hip_runtime.h>

typedef unsigned short u16;
typedef unsigned int u32;
typedef __attribute__((ext_vector_type(8))) short bf16x8;
typedef __attribute__((ext_vector_type(4))) float f32x4;
typedef const __attribute__((address_space(1))) void* gas1_t;
typedef __attribute__((address_space(3))) void* las3_t;

// Problem dims
#define T_LEN 512
#define B_SZ  64
#define D_SZ  1024
#define H_SZ  1024

// workspace layout (bytes), all 256-aligned
#define OFF_WX    0UL           // 8 MiB  bf16 Wx  [4096][1024]
#define OFF_WH    8388608UL     // 8 MiB  bf16 Wh  [4096][1024]
#define OFF_BIAS  16777216UL    // 16 KiB f32 bias[4096] = bx+bh
#define OFF_FLAGS 16793600UL    // 1 KiB: u32 cnt0 @ +0, cnt1 @ +256 (per-half barrier counters)
#define OFF_HROLL 16794624UL    // 64 MiB bf16 hroll[512][64][1024] (slot t = h input of step t)
#define OFF_XBF   83903488UL    // 64 MiB bf16 x [32768][1024]
#define OFF_XPROJ 151012352UL   // 256 MiB bf16 xprojP [512][gate(4)][hs(128)][brow(64)][jj(8)]

__device__ __forceinline__ u16 f2bf(float f) {
  u32 u = __builtin_bit_cast(u32, f);
  u += 0x7FFFu + ((u >> 16) & 1u);   // RNE
  return (u16)(u >> 16);
}
__device__ __forceinline__ float bf2f(u16 h) {
  u32 u = ((u32)h) << 16;
  return __builtin_bit_cast(float, u);
}

// ---------- phase 0: conversions ----------
__global__ __launch_bounds__(256) void cvt_f32_bf16(const float* __restrict__ in,
                                                    u16* __restrict__ out, int n) {
  int i = (blockIdx.x * 256 + threadIdx.x) * 4;
  if (i >= n) return;
  float4 v = *(const float4*)(in + i);
  ushort4 o;
  o.x = f2bf(v.x); o.y = f2bf(v.y); o.z = f2bf(v.z); o.w = f2bf(v.w);
  *(ushort4*)(out + i) = o;
}

__global__ __launch_bounds__(256) void bias_add(const float* __restrict__ a,
                                                const float* __restrict__ b,
                                                float* __restrict__ o) {
  int i = blockIdx.x * 256 + threadIdx.x;  // 4096 total
  o[i] = a[i] + b[i];
}

// ---------- phase 1: xproj = x @ Wx^T, written in PER-GATE PLANES ----------
// C layout: [t(512)][gate(4)][hs(128)][brow(64)][jj(8)] -- a wave's stores for
// one (mt,nt) cover full 64B lines (16B runs x 4 consecutive rows), unlike the
// old gate-interleaved layout's 2B/8B scatter (4x write amplification).
__global__ __launch_bounds__(256) void gemm_xproj(const u16* __restrict__ A,
                                                  const u16* __restrict__ Bw,
                                                  u16* __restrict__ C) {
  __shared__ __align__(16) u16 As[128 * 64];
  __shared__ __align__(16) u16 Bs[128 * 64];
  int wg = blockIdx.x;
  int swz = (wg & 7) * 1024 + (wg >> 3);  // XCD-aware bijective (8192 % 8 == 0)
  int mb = swz >> 5;
  int nb = swz & 31;
  int tid = threadIdx.x;
  int lane = tid & 63;
  int w = tid >> 6;
  int wm = w >> 1, wn = w & 1;

  int srow = lane >> 3;
  int scol = (lane & 7) * 8;
  const u16* Abase = A + (size_t)(mb * 128) * 1024;
  const u16* Bbase = Bw + (size_t)(nb * 128) * 1024;

  f32x4 acc[4][4];
#pragma unroll
  for (int i = 0; i < 4; ++i)
#pragma unroll
    for (int j = 0; j < 4; ++j) acc[i][j] = f32x4{0.f, 0.f, 0.f, 0.f};

  for (int k0 = 0; k0 < 1024; k0 += 64) {
#pragma unroll
    for (int r = 0; r < 4; ++r) {
      int chunk = w * 4 + r;
      int row = chunk * 8 + srow;
      __builtin_amdgcn_global_load_lds((gas1_t)(const void*)(Abase + (size_t)row * 1024 + k0 + scol),
                                       (las3_t)(void*)(&As[chunk * 512]), 16, 0, 0);
      __builtin_amdgcn_global_load_lds((gas1_t)(const void*)(Bbase + (size_t)row * 1024 + k0 + scol),
                                       (las3_t)(void*)(&Bs[chunk * 512]), 16, 0, 0);
    }
    __syncthreads();
#pragma unroll
    for (int kk = 0; kk < 64; kk += 32) {
      bf16x8 af[4], bfr[4];
#pragma unroll
      for (int mt = 0; mt < 4; ++mt)
        af[mt] = *(const bf16x8*)&As[(wm * 64 + mt * 16 + (lane & 15)) * 64 + kk + ((lane >> 4) << 3)];
#pragma unroll
      for (int nt = 0; nt < 4; ++nt)
        bfr[nt] = *(const bf16x8*)&Bs[(wn * 64 + nt * 16 + (lane & 15)) * 64 + kk + ((lane >> 4) << 3)];
#pragma unroll
      for (int mt = 0; mt < 4; ++mt)
#pragma unroll
        for (int nt = 0; nt < 4; ++nt)
          acc[mt][nt] = __builtin_amdgcn_mfma_f32_16x16x32_bf16(af[mt], bfr[nt], acc[mt][nt], 0, 0, 0);
    }
    __syncthreads();
  }
  int crowbase = mb * 128 + wm * 64;
  int ccolbase = nb * 128 + wn * 64;
#pragma unroll
  for (int mt = 0; mt < 4; ++mt)
#pragma unroll
    for (int nt = 0; nt < 4; ++nt) {
      int col = ccolbase + nt * 16 + (lane & 15);
      int gate = col >> 10;
      int hc = col & 1023;
      size_t cb = (size_t)gate * 65536 + (size_t)(hc >> 3) * 512 + (hc & 7);
#pragma unroll
      for (int r = 0; r < 4; ++r) {
        int row = crowbase + mt * 16 + ((lane >> 4) << 2) + r;
        C[(size_t)(row >> 6) * 262144 + cb + (size_t)(row & 63) * 8] = f2bf(acc[mt][nt][r]);
      }
    }
}

// ---------- phase 2: persistent sequential LSTM ----------
// R12 structure verbatim (128 WGs x 512 threads, 8-way K-partition, rolling
// cached h, write-through stores) with the barrier POLL changed from
// atomic_add(0) to a PLAIN sc0sc1 LOAD: atomics keep the counter line
// resident AT the LLC, and loads of it are serviced in parallel -- no RMW
// convoy through the LLC atomic unit (R9-R12 polls serialized there).
// Publish stays atomic_add(+1). xproj read side follows the per-gate-plane
// layout: 4 ushort prefetches bundled with the h store (vmcnt(4) drain).
__global__ __launch_bounds__(512, 2) void lstm_seq(const u16* __restrict__ xprojP,
                                                   const u16* __restrict__ Whb,
                                                   const float* __restrict__ bias,
                                                   u16* __restrict__ hroll,
                                                   u32* __restrict__ flags,
                                                   float* __restrict__ out) {
  __shared__ float pacc[64 * 272];  // 64 frags [kq][rt][f], rows padded to 17
#define PIDX(frag, row, col) (((frag) * 272) + (row) * 17 + (col))
  int wg = blockIdx.x;     // 0..127
  int bh = wg >> 6;        // batch half (independent barrier domain)
  int hw = wg & 63;        // 16-col slice (cols hw*16 .. hw*16+15)
  int tid = threadIdx.x;   // 0..511
  int lane = tid & 63;
  int kq = tid >> 6;       // wave = K-slice, 0..7 (128 k-cols each)
  int kw = kq << 7;        // k base
  int hi8 = (lane >> 4) << 3;

  // Wh fragments, register-resident: wf[f][ks], gate f, k = kq*128 + ks*32
  bf16x8 wf[4][4];
#pragma unroll
  for (int f = 0; f < 4; ++f) {
    int wrow = (f << 10) + (hw << 4) + (lane & 15);  // gate*1024 + out-col
#pragma unroll
    for (int ks = 0; ks < 4; ++ks)
      wf[f][ks] = *(const bf16x8*)&Whb[(size_t)wrow * 1024 + kw + ks * 32 + hi8];
  }

  int b = tid >> 4;                  // 0..31 batch row within half
  int jj = tid & 15;                 // 0..15 h-col within WG slice
  int hrow = (bh << 5) + b;
  int hcol = (hw << 4) + jj;
  float bs0 = bias[hcol], bs1 = bias[1024 + hcol], bs2 = bias[2048 + hcol], bs3 = bias[3072 + hcol];
  float c_state = 0.f;
  int am_row0 = (bh << 5) + (lane & 15);
  int am_row1 = am_row0 + 16;
  int mI = b >> 4, r16 = b & 15;
  u32* cnt = flags + (bh << 6);      // per-half counter, 256 B apart

  // per-gate-plane xproj pointer; per-step stride 262144 elems, gate stride 65536
  const u16* xpt = xprojP + (size_t)(hcol >> 3) * 512 + (size_t)hrow * 8 + (hcol & 7);
  u32 px0 = xpt[0], px1 = xpt[65536], px2 = xpt[131072], px3 = xpt[196608];  // t=0

  for (int t = 0; t < T_LEN; ++t) {
    // ---- h load: NORMAL CACHED from rolling slot t (virgin addresses) ----
    const u16* hcur = hroll + (size_t)t * 65536;
    const u16* p0 = hcur + (size_t)am_row0 * 1024 + kw + hi8;
    const u16* p1 = hcur + (size_t)am_row1 * 1024 + kw + hi8;
    bf16x8 a0[4], a1[4];
#pragma unroll
    for (int ks = 0; ks < 4; ++ks) {
      a0[ks] = *(const bf16x8*)(p0 + ks * 32);
      a1[ks] = *(const bf16x8*)(p1 + ks * 32);
    }

    // ---- MFMA: 8 accs (2 row-frags x 4 gates) over 4 k-steps ----
    f32x4 acc00 = f32x4{0.f, 0.f, 0.f, 0.f}, acc01 = acc00, acc02 = acc00, acc03 = acc00;
    f32x4 acc10 = acc00, acc11 = acc00, acc12 = acc00, acc13 = acc00;
#pragma unroll
    for (int ks = 0; ks < 4; ++ks) {
      acc00 = __builtin_amdgcn_mfma_f32_16x16x32_bf16(a0[ks], wf[0][ks], acc00, 0, 0, 0);
      acc01 = __builtin_amdgcn_mfma_f32_16x16x32_bf16(a0[ks], wf[1][ks], acc01, 0, 0, 0);
      acc02 = __builtin_amdgcn_mfma_f32_16x16x32_bf16(a0[ks], wf[2][ks], acc02, 0, 0, 0);
      acc03 = __builtin_amdgcn_mfma_f32_16x16x32_bf16(a0[ks], wf[3][ks], acc03, 0, 0, 0);
      acc10 = __builtin_amdgcn_mfma_f32_16x16x32_bf16(a1[ks], wf[0][ks], acc10, 0, 0, 0);
      acc11 = __builtin_amdgcn_mfma_f32_16x16x32_bf16(a1[ks], wf[1][ks], acc11, 0, 0, 0);
      acc12 = __builtin_amdgcn_mfma_f32_16x16x32_bf16(a1[ks], wf[2][ks], acc12, 0, 0, 0);
      acc13 = __builtin_amdgcn_mfma_f32_16x16x32_bf16(a1[ks], wf[3][ks], acc13, 0, 0, 0);
    }
    // ---- per-wave partials -> LDS: frag = kq*8 + rt*4 + f ----
    {
      int rbase = (lane >> 4) << 2;
      int cidx = lane & 15;
      int f0i = kq << 3;
#pragma unroll
      for (int r = 0; r < 4; ++r) {
        pacc[PIDX(f0i + 0, rbase + r, cidx)] = acc00[r];
        pacc[PIDX(f0i + 1, rbase + r, cidx)] = acc01[r];
        pacc[PIDX(f0i + 2, rbase + r, cidx)] = acc02[r];
        pacc[PIDX(f0i + 3, rbase + r, cidx)] = acc03[r];
        pacc[PIDX(f0i + 4, rbase + r, cidx)] = acc10[r];
        pacc[PIDX(f0i + 5, rbase + r, cidx)] = acc11[r];
        pacc[PIDX(f0i + 6, rbase + r, cidx)] = acc12[r];
        pacc[PIDX(f0i + 7, rbase + r, cidx)] = acc13[r];
      }
    }
    __syncthreads();
    // ---- reduce over 8 kq partials per gate ----
    float g[4];
#pragma unroll
    for (int f = 0; f < 4; ++f) {
      float s = 0.f;
#pragma unroll
      for (int k2 = 0; k2 < 8; ++k2)
        s += pacc[PIDX((k2 << 3) + (mI << 2) + f, r16, jj)];
      g[f] = s;
    }
    // tie the prefetched xproj words to a vmcnt before use (rule #18)
    asm volatile("s_waitcnt vmcnt(0)" : "+v"(px0), "+v"(px1), "+v"(px2), "+v"(px3));
    float gi = g[0] + bf2f((u16)px0) + bs0;
    float gf = g[1] + bf2f((u16)px1) + bs1;
    float go = g[2] + bf2f((u16)px2) + bs2;
    float gc = g[3] + bf2f((u16)px3) + bs3;
    float iv = 1.f / (1.f + __expf(-gi));
    float fv = 1.f / (1.f + __expf(-gf));
    float ov = 1.f / (1.f + __expf(-go));
    float cv = tanhf(gc);
    c_state = 1.f / (1.f + __expf(-(fv * c_state + iv * cv)));  // nonstandard, per reference
    float hn = tanhf(c_state) * ov;

    if (t == T_LEN - 1) {
      out[(size_t)hrow * 1024 + hcol] = hn;
    } else {
      // h store (write-through to slot t+1) + xproj(t+1) 4-gate prefetch +
      // counted drain: vmcnt(4) retires the OLDER store; loads fly through poll.
      u16* hdst = hroll + (size_t)(t + 1) * 65536 + (size_t)hrow * 1024 + hcol;
      const u16* xn0 = xpt + (size_t)(t + 1) * 262144;
      const u16* xn1 = xn0 + 65536;
      const u16* xn2 = xn0 + 131072;
      const u16* xn3 = xn0 + 196608;
      u32 hb = (u32)f2bf(hn);
      asm volatile(
          "global_store_short %4, %9, off sc0 sc1\n\t"
          "global_load_ushort %0, %5, off\n\t"
          "global_load_ushort %1, %6, off\n\t"
          "global_load_ushort %2, %7, off\n\t"
          "global_load_ushort %3, %8, off\n\t"
          "s_waitcnt vmcnt(4)"
          : "=&v"(px0), "=&v"(px1), "=&v"(px2), "=&v"(px3)
          : "v"(hdst), "v"(xn0), "v"(xn1), "v"(xn2), "v"(xn3), "v"(hb)
          : "memory");
      __syncthreads();  // all 8 waves' stores drained; pacc reads done
      if (tid == 0) {
        // publish: fire-and-forget atomic increment (performed at the LLC;
        // keeps the counter line LLC-resident)
        u32 one = 1u;
        asm volatile("global_atomic_add %0, %1, off" :: "v"(cnt), "v"(one) : "memory");
        // poll: PLAIN sc0sc1 load -- parallel read of the LLC-resident line,
        // no RMW serialization through the atomic unit (the R9-R12 convoy)
        u32 tgt = (u32)((t + 1) << 6);  // 64 publishers per domain
        u32 f;
        for (;;) {
          asm volatile("global_load_dword %0, %1, off sc0 sc1\n\ts_waitcnt vmcnt(0)"
                       : "=&v"(f) : "v"(cnt) : "memory");
          if (f >= tgt) break;
        }
      }
      __syncthreads();
    }
  }
}

extern "C" void kernel_launch(void* const* d_in, const int* in_sizes, int n_in,
                              void* d_out, int out_size, void* d_ws, size_t ws_size,
                              hipStream_t stream) {
  const float* x  = (const float*)d_in[0];   // [512][64][1024]
  const float* Wx = (const float*)d_in[1];   // [4][1024][1024]
  const float* bx = (const float*)d_in[2];   // [4][1024]
  const float* Wh = (const float*)d_in[3];   // [4][1024][1024]
  const float* bh = (const float*)d_in[4];   // [4][1024]
  float* out = (float*)d_out;                // [64][1024]
  char* ws = (char*)d_ws;

  u16* wx_bf  = (u16*)(ws + OFF_WX);
  u16* wh_bf  = (u16*)(ws + OFF_WH);
  float* bias = (float*)(ws + OFF_BIAS);
  u32* flags  = (u32*)(ws + OFF_FLAGS);
  u16* hroll  = (u16*)(ws + OFF_HROLL);
  u16* x_bf   = (u16*)(ws + OFF_XBF);
  u16* xproj  = (u16*)(ws + OFF_XPROJ);

  // per-launch: zero counters (1 KiB) + rolling slot 0 (h_0 = 0, 128 KiB) -- contiguous
  hipMemsetAsync(ws + OFF_FLAGS, 0, 1024 + 131072, stream);

  cvt_f32_bf16<<<4096, 256, 0, stream>>>(Wx, wx_bf, 4194304);
  cvt_f32_bf16<<<4096, 256, 0, stream>>>(Wh, wh_bf, 4194304);
  bias_add<<<16, 256, 0, stream>>>(bx, bh, bias);
  cvt_f32_bf16<<<32768, 256, 0, stream>>>(x, x_bf, 33554432);
  gemm_xproj<<<8192, 256, 0, stream>>>(x_bf, wx_bf, xproj);
  lstm_seq<<<128, 512, 0, stream>>>(xproj, wh_bf, bias, hroll, flags, out);
}

// Round 15
// 2837.396 us; speedup vs baseline: 1.7501x; 1.1598x over previous
//
#include <hip/hip_runtime.h>

typedef unsigned short u16;
typedef unsigned int u32;
typedef __attribute__((ext_vector_type(8))) short bf16x8;
typedef __attribute__((ext_vector_type(4))) float f32x4;
typedef __attribute__((ext_vector_type(4))) u32 u32x4;
typedef const __attribute__((address_space(1))) void* gas1_t;
typedef __attribute__((address_space(3))) void* las3_t;

// Problem dims
#define T_LEN 512
#define B_SZ  64
#define D_SZ  1024
#define H_SZ  1024

// workspace layout (bytes), all 256-aligned
#define OFF_WX    0UL           // 8 MiB  bf16 Wx  [4096][1024]
#define OFF_WH    8388608UL     // 8 MiB  bf16 Wh  [4096][1024]
#define OFF_BIAS  16777216UL    // 16 KiB f32 bias[4096] = bx+bh
#define OFF_FLAGS 16793600UL    // 2 KiB: cnt0 @+0, cnt1 @+256 (lstm barrier); cnt_x[256] @+1024 (gemm slab counters)
#define OFF_HROLL 16795648UL    // 64 MiB bf16 hroll[512][64][1024]
#define OFF_XBF   83904512UL    // 64 MiB bf16 x [32768][1024]
#define OFF_XPROJ 151013376UL   // 256 MiB bf16 xprojP [512][gate(4)][hs(128)][brow(64)][jj(8)]

__device__ __forceinline__ u16 f2bf(float f) {
  u32 u = __builtin_bit_cast(u32, f);
  u += 0x7FFFu + ((u >> 16) & 1u);   // RNE
  return (u16)(u >> 16);
}
__device__ __forceinline__ float bf2f(u16 h) {
  u32 u = ((u32)h) << 16;
  return __builtin_bit_cast(float, u);
}

// ---------- phase 0: conversions ----------
__global__ __launch_bounds__(256) void cvt_f32_bf16(const float* __restrict__ in,
                                                    u16* __restrict__ out, int n) {
  int i = (blockIdx.x * 256 + threadIdx.x) * 4;
  if (i >= n) return;
  float4 v = *(const float4*)(in + i);
  ushort4 o;
  o.x = f2bf(v.x); o.y = f2bf(v.y); o.z = f2bf(v.z); o.w = f2bf(v.w);
  *(ushort4*)(out + i) = o;
}

__global__ __launch_bounds__(256) void bias_add(const float* __restrict__ a,
                                                const float* __restrict__ b,
                                                float* __restrict__ o) {
  int i = blockIdx.x * 256 + threadIdx.x;  // 4096 total
  o[i] = a[i] + b[i];
}

// ---------- fused phase 1+2: producer-consumer ----------
// 256 WGs x 512 threads. WGs 0..127: lstm consumer (R14 structure verbatim).
// WGs 128..255: persistent gemm producer -- 64 tiles each, t-major order:
// idx = tp*32 + nb, tile = rows tp*128 (2 timesteps) x cols nb*128. Epilogue
// stores are sc0sc1 write-through (LLC-visible), drained by vmcnt(0), then
// tid0 publishes atomic cnt_x[tp]++. Consumer gates its xproj prefetch on
// cnt_x[tp]==32 (quad-poll, local watermark -> ~1 LLC read per 8 steps after
// ramp). xproj addresses are virgin per launch -> consumer's cached reads are
// staleness-safe (hroll argument); replays rewrite identical values.
__global__ __launch_bounds__(512, 2) void lstm_fused(const u16* __restrict__ A,     // x_bf
                                                     const u16* __restrict__ Bw,    // wx_bf
                                                     u16* __restrict__ xprojP,
                                                     const u16* __restrict__ Whb,
                                                     const float* __restrict__ bias,
                                                     u16* __restrict__ hroll,
                                                     u32* __restrict__ flags,
                                                     float* __restrict__ out) {
  __shared__ __align__(16) char smem[69632];
  int wg = blockIdx.x;
  int tid = threadIdx.x;   // 0..511
  int lane = tid & 63;
  int w = tid >> 6;        // 0..7
  int hi8 = (lane >> 4) << 3;
  u32* cntx = flags + 256;  // cnt_x[256] @ byte offset +1024

  if (wg >= 128) {
    // ================= GEMM PRODUCER =================
    u16* As = (u16*)smem;              // [128][64]
    u16* Bs = (u16*)(smem + 16384);    // [128][64]
    int g = wg - 128;                  // 0..127
    int wm = w >> 1, wn = w & 1;       // wave grid 4x2 on 128x128
    int col8 = (lane & 7) * 8;
    int rowL = w * 8 + (lane >> 3);    // staging row within 64-row round

    for (int idx = g; idx < 8192; idx += 128) {
      int tp = idx >> 5;               // 0..255 (rows tp*128 = steps 2tp,2tp+1)
      int nb = idx & 31;               // col tile
      const u16* At = A + (size_t)tp * 131072;
      const u16* Bt = Bw + (size_t)nb * 131072;

      f32x4 acc[2][4];
#pragma unroll
      for (int mt = 0; mt < 2; ++mt)
#pragma unroll
        for (int nt = 0; nt < 4; ++nt) acc[mt][nt] = f32x4{0.f, 0.f, 0.f, 0.f};

      for (int k0 = 0; k0 < 1024; k0 += 64) {
#pragma unroll
        for (int r = 0; r < 2; ++r) {
          int row = r * 64 + rowL;
          int dst = r * 4096 + w * 512;  // + lane*8 implicit (wave-uniform base)
          __builtin_amdgcn_global_load_lds((gas1_t)(const void*)(At + (size_t)row * 1024 + k0 + col8),
                                           (las3_t)(void*)(&As[dst]), 16, 0, 0);
          __builtin_amdgcn_global_load_lds((gas1_t)(const void*)(Bt + (size_t)row * 1024 + k0 + col8),
                                           (las3_t)(void*)(&Bs[dst]), 16, 0, 0);
        }
        __syncthreads();
#pragma unroll
        for (int kk = 0; kk < 64; kk += 32) {
          bf16x8 af[2], bfr[4];
#pragma unroll
          for (int mt = 0; mt < 2; ++mt)
            af[mt] = *(const bf16x8*)&As[(wm * 32 + mt * 16 + (lane & 15)) * 64 + kk + hi8];
#pragma unroll
          for (int nt = 0; nt < 4; ++nt)
            bfr[nt] = *(const bf16x8*)&Bs[(wn * 64 + nt * 16 + (lane & 15)) * 64 + kk + hi8];
#pragma unroll
          for (int mt = 0; mt < 2; ++mt)
#pragma unroll
            for (int nt = 0; nt < 4; ++nt)
              acc[mt][nt] = __builtin_amdgcn_mfma_f32_16x16x32_bf16(af[mt], bfr[nt], acc[mt][nt], 0, 0, 0);
        }
        __syncthreads();
      }
      // epilogue: per-gate-plane layout, write-through stores (LLC-visible)
#pragma unroll
      for (int mt = 0; mt < 2; ++mt)
#pragma unroll
        for (int nt = 0; nt < 4; ++nt) {
          int col = nb * 128 + wn * 64 + nt * 16 + (lane & 15);
          int gate = col >> 10;
          int hc = col & 1023;
          size_t cb = (size_t)gate * 65536 + (size_t)(hc >> 3) * 512 + (hc & 7);
#pragma unroll
          for (int r = 0; r < 4; ++r) {
            int row = tp * 128 + wm * 32 + mt * 16 + ((lane >> 4) << 2) + r;
            u16* cp = xprojP + (size_t)(row >> 6) * 262144 + cb + (size_t)(row & 63) * 8;
            u32 val = (u32)f2bf(acc[mt][nt][r]);
            asm volatile("global_store_short %0, %1, off sc0 sc1" :: "v"(cp), "v"(val) : "memory");
          }
        }
      asm volatile("s_waitcnt vmcnt(0)" ::: "memory");
      __syncthreads();  // all waves' stores drained
      if (tid == 0) {
        u32 one = 1u;
        u32* cp = cntx + tp;
        asm volatile("global_atomic_add %0, %1, off" :: "v"(cp), "v"(one) : "memory");
      }
      // no sync needed before next tile's staging: staging writes As/Bs only
      // after the next __syncthreads (inside k0 loop, post-issue) -- but
      // LDS reuse across tiles needs all waves past the epilogue reads of
      // As/Bs... epilogue reads only registers; the vmcnt+sync above covers.
    }
    return;
  }

  // ================= LSTM CONSUMER (R14 structure) =================
  float* pacc = (float*)smem;  // 64 frags [kq][rt][f], rows padded to 17
#define PIDX(frag, row, col) (((frag) * 272) + (row) * 17 + (col))
  int bh = wg >> 6;        // batch half (independent barrier domain)
  int hw = wg & 63;        // 16-col slice
  int kq = w;              // wave = K-slice, 0..7 (128 k-cols each)
  int kw = kq << 7;

  bf16x8 wf[4][4];
#pragma unroll
  for (int f = 0; f < 4; ++f) {
    int wrow = (f << 10) + (hw << 4) + (lane & 15);
#pragma unroll
    for (int ks = 0; ks < 4; ++ks)
      wf[f][ks] = *(const bf16x8*)&Whb[(size_t)wrow * 1024 + kw + ks * 32 + hi8];
  }

  int b = tid >> 4;
  int jj = tid & 15;
  int hrow = (bh << 5) + b;
  int hcol = (hw << 4) + jj;
  float bs0 = bias[hcol], bs1 = bias[1024 + hcol], bs2 = bias[2048 + hcol], bs3 = bias[3072 + hcol];
  float c_state = 0.f;
  int am_row0 = (bh << 5) + (lane & 15);
  int am_row1 = am_row0 + 16;
  int mI = b >> 4, r16 = b & 15;
  u32* cnt = flags + (bh << 6);

  const u16* xpt = xprojP + (size_t)(hcol >> 3) * 512 + (size_t)hrow * 8 + (hcol & 7);
  int ready_tp = 0;  // tps known complete (local watermark)

  // gate + prefetch for t=0 (slab tp=0)
  {
    const u32* cp = cntx;  // quad base 0
    for (;;) {
      u32x4 c4;
      asm volatile("global_load_dwordx4 %0, %1, off sc0 sc1\n\ts_waitcnt vmcnt(0)"
                   : "=&v"(c4) : "v"(cp) : "memory");
      if (c4[0] >= 32u) {
        ready_tp = 1;
        if (c4[1] >= 32u) { ready_tp = 2;
          if (c4[2] >= 32u) { ready_tp = 3;
            if (c4[3] >= 32u) ready_tp = 4; } }
        break;
      }
    }
  }
  u32 px0 = xpt[0], px1 = xpt[65536], px2 = xpt[131072], px3 = xpt[196608];

  for (int t = 0; t < T_LEN; ++t) {
    // h load: NORMAL CACHED from rolling slot t (virgin addresses)
    const u16* hcur = hroll + (size_t)t * 65536;
    const u16* p0 = hcur + (size_t)am_row0 * 1024 + kw + hi8;
    const u16* p1 = hcur + (size_t)am_row1 * 1024 + kw + hi8;
    bf16x8 a0[4], a1[4];
#pragma unroll
    for (int ks = 0; ks < 4; ++ks) {
      a0[ks] = *(const bf16x8*)(p0 + ks * 32);
      a1[ks] = *(const bf16x8*)(p1 + ks * 32);
    }

    f32x4 acc00 = f32x4{0.f, 0.f, 0.f, 0.f}, acc01 = acc00, acc02 = acc00, acc03 = acc00;
    f32x4 acc10 = acc00, acc11 = acc00, acc12 = acc00, acc13 = acc00;
#pragma unroll
    for (int ks = 0; ks < 4; ++ks) {
      acc00 = __builtin_amdgcn_mfma_f32_16x16x32_bf16(a0[ks], wf[0][ks], acc00, 0, 0, 0);
      acc01 = __builtin_amdgcn_mfma_f32_16x16x32_bf16(a0[ks], wf[1][ks], acc01, 0, 0, 0);
      acc02 = __builtin_amdgcn_mfma_f32_16x16x32_bf16(a0[ks], wf[2][ks], acc02, 0, 0, 0);
      acc03 = __builtin_amdgcn_mfma_f32_16x16x32_bf16(a0[ks], wf[3][ks], acc03, 0, 0, 0);
      acc10 = __builtin_amdgcn_mfma_f32_16x16x32_bf16(a1[ks], wf[0][ks], acc10, 0, 0, 0);
      acc11 = __builtin_amdgcn_mfma_f32_16x16x32_bf16(a1[ks], wf[1][ks], acc11, 0, 0, 0);
      acc12 = __builtin_amdgcn_mfma_f32_16x16x32_bf16(a1[ks], wf[2][ks], acc12, 0, 0, 0);
      acc13 = __builtin_amdgcn_mfma_f32_16x16x32_bf16(a1[ks], wf[3][ks], acc13, 0, 0, 0);
    }
    {
      int rbase = (lane >> 4) << 2;
      int cidx = lane & 15;
      int f0i = kq << 3;
#pragma unroll
      for (int r = 0; r < 4; ++r) {
        pacc[PIDX(f0i + 0, rbase + r, cidx)] = acc00[r];
        pacc[PIDX(f0i + 1, rbase + r, cidx)] = acc01[r];
        pacc[PIDX(f0i + 2, rbase + r, cidx)] = acc02[r];
        pacc[PIDX(f0i + 3, rbase + r, cidx)] = acc03[r];
        pacc[PIDX(f0i + 4, rbase + r, cidx)] = acc10[r];
        pacc[PIDX(f0i + 5, rbase + r, cidx)] = acc11[r];
        pacc[PIDX(f0i + 6, rbase + r, cidx)] = acc12[r];
        pacc[PIDX(f0i + 7, rbase + r, cidx)] = acc13[r];
      }
    }
    __syncthreads();
    float g[4];
#pragma unroll
    for (int f = 0; f < 4; ++f) {
      float s = 0.f;
#pragma unroll
      for (int k2 = 0; k2 < 8; ++k2)
        s += pacc[PIDX((k2 << 3) + (mI << 2) + f, r16, jj)];
      g[f] = s;
    }
    asm volatile("s_waitcnt vmcnt(0)" : "+v"(px0), "+v"(px1), "+v"(px2), "+v"(px3));
    float gi = g[0] + bf2f((u16)px0) + bs0;
    float gf = g[1] + bf2f((u16)px1) + bs1;
    float go = g[2] + bf2f((u16)px2) + bs2;
    float gc = g[3] + bf2f((u16)px3) + bs3;
    float iv = 1.f / (1.f + __expf(-gi));
    float fv = 1.f / (1.f + __expf(-gf));
    float ov = 1.f / (1.f + __expf(-go));
    float cv = tanhf(gc);
    c_state = 1.f / (1.f + __expf(-(fv * c_state + iv * cv)));  // nonstandard, per reference
    float hn = tanhf(c_state) * ov;

    if (t == T_LEN - 1) {
      out[(size_t)hrow * 1024 + hcol] = hn;
    } else {
      // h store (write-through)
      u16* hdst = hroll + (size_t)(t + 1) * 65536 + (size_t)hrow * 1024 + hcol;
      u32 hb = (u32)f2bf(hn);
      asm volatile("global_store_short %0, %1, off sc0 sc1" :: "v"(hdst), "v"(hb) : "memory");
      // gate: slab for step t+1 must be published (ramp-only in steady state)
      int tpn = (t + 1) >> 1;
      if (tpn >= ready_tp) {
        const u32* cp = cntx + (tpn & ~3);
        int q = tpn & 3;
        for (;;) {
          u32x4 c4;
          asm volatile("global_load_dwordx4 %0, %1, off sc0 sc1\n\ts_waitcnt vmcnt(0)"
                       : "=&v"(c4) : "v"(cp) : "memory");
          u32 v0 = c4[0], v1 = c4[1], v2 = c4[2], v3 = c4[3];
          bool b0 = v0 >= 32u, b1 = v1 >= 32u, b2 = v2 >= 32u, b3 = v3 >= 32u;
          bool mine = (q == 0) ? b0 : (q == 1) ? b1 : (q == 2) ? b2 : b3;
          if (mine) {
            int ext = (q == 0) ? (b1 ? (b2 ? (b3 ? 4 : 3) : 2) : 1)
                    : (q == 1) ? (b2 ? (b3 ? 3 : 2) : 1)
                    : (q == 2) ? (b3 ? 2 : 1) : 1;
            ready_tp = tpn + ext;
            break;
          }
        }
      }
      // xproj(t+1) prefetch (plain cached; lines virgin -> post-publish fills)
      const u16* xn0 = xpt + (size_t)(t + 1) * 262144;
      const u16* xn1 = xn0 + 65536;
      const u16* xn2 = xn0 + 131072;
      const u16* xn3 = xn0 + 196608;
      asm volatile(
          "global_load_ushort %0, %4, off\n\t"
          "global_load_ushort %1, %5, off\n\t"
          "global_load_ushort %2, %6, off\n\t"
          "global_load_ushort %3, %7, off"
          : "=&v"(px0), "=&v"(px1), "=&v"(px2), "=&v"(px3)
          : "v"(xn0), "v"(xn1), "v"(xn2), "v"(xn3)
          : "memory");
      // retire the h store (oldest VMEM op; 4 prefetch loads stay in flight)
      asm volatile("s_waitcnt vmcnt(4)" ::: "memory");
      __syncthreads();  // all 8 waves' stores drained; pacc reads done
      if (tid == 0) {
        u32 one = 1u;
        asm volatile("global_atomic_add %0, %1, off" :: "v"(cnt), "v"(one) : "memory");
        u32 tgt = (u32)((t + 1) << 6);  // 64 publishers per domain
        u32 f;
        for (;;) {
          asm volatile("global_load_dword %0, %1, off sc0 sc1\n\ts_waitcnt vmcnt(0)"
                       : "=&v"(f) : "v"(cnt) : "memory");
          if (f >= tgt) break;
        }
      }
      __syncthreads();
    }
  }
}

extern "C" void kernel_launch(void* const* d_in, const int* in_sizes, int n_in,
                              void* d_out, int out_size, void* d_ws, size_t ws_size,
                              hipStream_t stream) {
  const float* x  = (const float*)d_in[0];   // [512][64][1024]
  const float* Wx = (const float*)d_in[1];   // [4][1024][1024]
  const float* bx = (const float*)d_in[2];   // [4][1024]
  const float* Wh = (const float*)d_in[3];   // [4][1024][1024]
  const float* bh = (const float*)d_in[4];   // [4][1024]
  float* out = (float*)d_out;                // [64][1024]
  char* ws = (char*)d_ws;

  u16* wx_bf  = (u16*)(ws + OFF_WX);
  u16* wh_bf  = (u16*)(ws + OFF_WH);
  float* bias = (float*)(ws + OFF_BIAS);
  u32* flags  = (u32*)(ws + OFF_FLAGS);
  u16* hroll  = (u16*)(ws + OFF_HROLL);
  u16* x_bf   = (u16*)(ws + OFF_XBF);
  u16* xproj  = (u16*)(ws + OFF_XPROJ);

  // per-launch: zero barrier counters + slab counters (2 KiB) + hroll slot 0
  // (128 KiB) -- contiguous region
  hipMemsetAsync(ws + OFF_FLAGS, 0, 2048 + 131072, stream);

  cvt_f32_bf16<<<4096, 256, 0, stream>>>(Wx, wx_bf, 4194304);
  cvt_f32_bf16<<<4096, 256, 0, stream>>>(Wh, wh_bf, 4194304);
  bias_add<<<16, 256, 0, stream>>>(bx, bh, bias);
  cvt_f32_bf16<<<32768, 256, 0, stream>>>(x, x_bf, 33554432);
  lstm_fused<<<256, 512, 0, stream>>>(x_bf, wx_bf, xproj, wh_bf, bias, hroll, flags, out);
}